// Round 7
// baseline (78.522 us; speedup 1.0000x reference)
//
#include <hip/hip_runtime.h>
#include <hip/hip_bf16.h>

typedef __attribute__((ext_vector_type(8))) short short8v;
typedef __attribute__((ext_vector_type(4))) float f32x4;

static constexpr int B_ = 4, S_ = 2048, E_ = 768, H_ = 12, D_ = 64;
static constexpr int NROWS = B_ * H_ * S_;       // 98304
static constexpr float LOG2E = 1.44269504088896340736f;
static constexpr float LN2 = 0.69314718055994530942f;

typedef __attribute__((address_space(3))) unsigned int lds_u32;
typedef const __attribute__((address_space(1))) unsigned int glb_u32;

__device__ __forceinline__ void gload16(const void* g, void* l) {
  __builtin_amdgcn_global_load_lds((glb_u32*)g, (lds_u32*)l, 16, 0, 0);
}

#define VM0 asm volatile("s_waitcnt vmcnt(0)" ::: "memory")
#define VM2 asm volatile("s_waitcnt vmcnt(2)" ::: "memory")
#define LG0 asm volatile("s_waitcnt lgkmcnt(0)" ::: "memory")
#define BAR __builtin_amdgcn_s_barrier()

__device__ __forceinline__ unsigned short f2bf(float f) {
  union { float f; unsigned int u; } v; v.f = f;
  unsigned int u = v.u;
  unsigned int r = (u + 0x7fffu + ((u >> 16) & 1u)) >> 16;
  return (unsigned short)r;
}

// wb[1536][768]: rows 0..767 = beta[h]*log2e*W^Q; rows 768..1535 = W^K
__global__ __launch_bounds__(256) void cvt_w_kernel(const float4* __restrict__ wq,
                                                    const float4* __restrict__ wk,
                                                    const float* __restrict__ beta,
                                                    ushort4* __restrict__ wb, int n4) {
  int i = blockIdx.x * 256 + threadIdx.x;
  if (i < n4) {
    int row = i / (E_ / 4);
    float sc = beta[row >> 6] * LOG2E;
    float4 v = wq[i];
    ushort4 o;
    o.x = f2bf(v.x * sc); o.y = f2bf(v.y * sc); o.z = f2bf(v.z * sc); o.w = f2bf(v.w * sc);
    wb[i] = o;
  } else if (i < 2 * n4) {
    int j = i - n4;
    float4 v = wk[j];
    ushort4 o;
    o.x = f2bf(v.x); o.y = f2bf(v.y); o.z = f2bf(v.z); o.w = f2bf(v.w);
    wb[i] = o;
  }
}

// GEMM: C[8192,1536] = X[8192,768] * W[1536,768]^T, 128x128 tile, BK=32.
// r7: lse's proven schedule ported in -- ONE barrier per k-step (was 2),
// B triple-buffered in LDS staged TWO steps ahead (vmcnt(2) steady state
// leaves B(i+1) in flight; never drained to 0 until the last step), A-regs
// one step ahead (r6), A double-buffered in LDS. vmcnt ledger at step i:
// outstanding = [B(i) x2 oldest, a(i) x4, B(i+1) x2 newest] -> VM2 drains
// exactly B(i)+a(i). Buffer-reuse safety: stage(i)->lB[(i+2)%3] was last
// read at step i-1, and BAR(i) separates those reads from the stage (same
// proof as lse's 3-buffer rotation); lA[i&1] rewrite at i+2 is fenced by
// BAR(i+1). Chunk-XOR swizzle (c ^= row&3) on both operands as in r6.
__global__ __launch_bounds__(256) void proj_kernel(const float* __restrict__ x,
                                                   const unsigned short* __restrict__ wb,
                                                   unsigned short* __restrict__ Qb,
                                                   unsigned short* __restrict__ Kb) {
  __shared__ unsigned short lA[2][128 * 32];    // 2 x 8 KB bf16
  __shared__ unsigned short lB[3][128 * 32];    // 3 x 8 KB bf16
  const int mt = blockIdx.x, nt = blockIdx.y;
  const int t = threadIdx.x;
  const int wid = t >> 6, lane = t & 63, l15 = lane & 15, lhi = lane >> 4;
  const int wr = (wid >> 1) * 64, wc = (wid & 1) * 64;

  f32x4 acc[4][4] = {};

  const int row = t >> 2, ch = t & 3;           // row 0..63, dest chunk 0..3
  const int chs = ch ^ (row & 3);               // inverse-swizzled source chunk
  const float* gA = x + (size_t)(mt * 128 + row) * E_ + chs * 8;
  const unsigned short* gB = wb + (size_t)(nt * 128 + row) * E_ + chs * 8;

  // prologue: a(0) f32 loads, then B(0), B(1) stages (order matters for VM2)
  f32x4 a0 = *(const f32x4*)(gA);
  f32x4 a1 = *(const f32x4*)(gA + 4);
  f32x4 a2 = *(const f32x4*)(gA + 64 * E_);
  f32x4 a3 = *(const f32x4*)(gA + 64 * E_ + 4);
  gload16(gB, &lB[0][t * 8]);
  gload16(gB + (size_t)64 * E_, &lB[0][2048 + t * 8]);
  gload16(gB + 32, &lB[1][t * 8]);
  gload16(gB + (size_t)64 * E_ + 32, &lB[1][2048 + t * 8]);

  int cb = 0, sb = 2;                           // read buf = i%3, stage buf = (i+2)%3
#pragma unroll 1
  for (int i = 0; i < 24; ++i) {
    const int k0 = i * 32;
    if (i == 23) { VM0; } else { VM2; }         // B(i)+a(i) landed; B(i+1) in flight
    union { short8v s8; unsigned int u[4]; } c0, c1;
    asm("v_cvt_pk_bf16_f32 %0, %1, %2" : "=v"(c0.u[0]) : "v"(a0[0]), "v"(a0[1]));
    asm("v_cvt_pk_bf16_f32 %0, %1, %2" : "=v"(c0.u[1]) : "v"(a0[2]), "v"(a0[3]));
    asm("v_cvt_pk_bf16_f32 %0, %1, %2" : "=v"(c0.u[2]) : "v"(a1[0]), "v"(a1[1]));
    asm("v_cvt_pk_bf16_f32 %0, %1, %2" : "=v"(c0.u[3]) : "v"(a1[2]), "v"(a1[3]));
    asm("v_cvt_pk_bf16_f32 %0, %1, %2" : "=v"(c1.u[0]) : "v"(a2[0]), "v"(a2[1]));
    asm("v_cvt_pk_bf16_f32 %0, %1, %2" : "=v"(c1.u[1]) : "v"(a2[2]), "v"(a2[3]));
    asm("v_cvt_pk_bf16_f32 %0, %1, %2" : "=v"(c1.u[2]) : "v"(a3[0]), "v"(a3[1]));
    asm("v_cvt_pk_bf16_f32 %0, %1, %2" : "=v"(c1.u[3]) : "v"(a3[2]), "v"(a3[3]));
    *(short8v*)&lA[i & 1][row * 32 + ch * 8] = c0.s8;          // rows 0..63
    *(short8v*)&lA[i & 1][(row + 64) * 32 + ch * 8] = c1.s8;   // rows 64..127
    LG0;                                        // own ds_writes visible
    BAR;                                        // lA[i&1]+lB[cb] staged block-wide
    if (i < 23) {                               // a(i+1): issued before B(i+2)
      a0 = *(const f32x4*)(gA + k0 + 32);
      a1 = *(const f32x4*)(gA + k0 + 36);
      a2 = *(const f32x4*)(gA + 64 * E_ + k0 + 32);
      a3 = *(const f32x4*)(gA + 64 * E_ + k0 + 36);
    }
    if (i < 22) {                               // stage B(i+2) -> lB[sb]
      gload16(gB + k0 + 64, &lB[sb][t * 8]);
      gload16(gB + (size_t)64 * E_ + k0 + 64, &lB[sb][2048 + t * 8]);
    }
    short8v aF[4], bF[4];
    const unsigned short* pa = lA[i & 1];
    const unsigned short* pb = lB[cb];
#pragma unroll
    for (int m = 0; m < 4; ++m) {
      const int r = wr + m * 16 + l15;
      aF[m] = *(const short8v*)&pa[r * 32 + ((lhi ^ (l15 & 3)) << 3)];
    }
#pragma unroll
    for (int n = 0; n < 4; ++n) {
      const int r = wc + n * 16 + l15;
      bF[n] = *(const short8v*)&pb[r * 32 + ((lhi ^ (l15 & 3)) << 3)];
    }
#pragma unroll
    for (int m = 0; m < 4; ++m)
#pragma unroll
      for (int n = 0; n < 4; ++n)
        acc[m][n] = __builtin_amdgcn_mfma_f32_16x16x32_bf16(aF[m], bF[n], acc[m][n], 0, 0, 0);
    cb = (cb == 2) ? 0 : cb + 1;
    sb = (sb == 2) ? 0 : sb + 1;
  }

  const int nbase = nt * 128 + wc;
  unsigned short* dst = (nbase < 768) ? Qb : Kb;
  const int nb = (nbase < 768) ? nbase : nbase - 768;
#pragma unroll
  for (int m = 0; m < 4; ++m)
#pragma unroll
    for (int n = 0; n < 4; ++n)
#pragma unroll
      for (int r = 0; r < 4; ++r) {
        int M = mt * 128 + wr + m * 16 + lhi * 4 + r;
        int col = nb + n * 16 + l15;
        int h = col >> 6, d = col & 63;
        int b = M >> 11, s = M & (S_ - 1);
        dst[((((size_t)b * H_ + h) * S_ + s) << 6) + d] = f2bf(acc[m][n][r]);
      }
}

// Stage one 64-row K tile (8 KB) into LDS (256 threads), XOR-swizzled via
// pre-swizzled global source (rule #21: linear LDS dest).
// LDS[row][slot] (16B chunks, slot=0..7) = K[row][slot ^ (row&7)].
__device__ __forceinline__ void stageK(const unsigned short* __restrict__ Kbase, int t0,
                                       int tid, unsigned short* lbuf) {
  const int w = tid >> 6;
  const int r = tid >> 3;                       // 0..31
  const int c = (tid & 7) ^ (r & 7);            // inverse-swizzled source chunk
  const char* src = (const char*)Kbase + ((size_t)(t0 + r) << 7) + (c << 4);
  char* ldst = (char*)lbuf + (w << 10);         // wave-uniform; HW adds lane*16
  gload16(src, ldst);
  gload16(src + (32 << 7), ldst + 4096);        // rows 32..63, same swizzle
}

// 64 q-rows per wave: K-fragments read once from LDS feed 4 row-blocks.
// Diagonal self-exclusion folded in (bit-exact r1-r6): zero the diag
// element of fragment (rb==f) instead of a separate correction pass.
__device__ __forceinline__ void computeTile64(const unsigned short* lbuf, const short8v q[4][2],
                                              f32x4 sp[4], bool isD, int l15, int lhi) {
  short8v kf[4][2];
  const int sw = l15 & 7;
#pragma unroll
  for (int f = 0; f < 4; ++f) {
    const char* p = (const char*)lbuf + ((f * 16 + l15) << 7);
    kf[f][0] = *(const short8v*)(p + ((lhi ^ sw) << 4));
    kf[f][1] = *(const short8v*)(p + (((lhi + 4) ^ sw) << 4));
  }
#pragma unroll
  for (int rb = 0; rb < 4; ++rb) {
    f32x4 acc[4] = {};
#pragma unroll
    for (int f = 0; f < 4; ++f) {
      acc[f] = __builtin_amdgcn_mfma_f32_16x16x32_bf16(q[rb][0], kf[f][0], acc[f], 0, 0, 0);
      acc[f] = __builtin_amdgcn_mfma_f32_16x16x32_bf16(q[rb][1], kf[f][1], acc[f], 0, 0, 0);
    }
#pragma unroll
    for (int f = 0; f < 4; ++f) {
      f32x4 e;
#pragma unroll
      for (int r = 0; r < 4; ++r) e[r] = __builtin_amdgcn_exp2f(acc[f][r]);
      if (isD && f == rb) {
#pragma unroll
        for (int r = 0; r < 4; ++r)
          if (l15 == lhi * 4 + r) e[r] = 0.f;
      }
      sp[rb] += e;                        // v_pk_add_f32 x2
    }
  }
}

// LSE row sums. 4 waves x 64 rows = 256 rows/block; t-range split in 4
// (8 tiles/block). 3-buffer rotation, one barrier per tile (proven best
// operating point across r0-r6: deeper pipelines/LDS-free/reg-dbuf all
// regress or tie; lse plateaus at ~45us, exp2-VALU dominated).
__global__ __launch_bounds__(256) void lse_kernel(const unsigned short* __restrict__ Qb,
                                                  const unsigned short* __restrict__ Kb,
                                                  float* __restrict__ rowsum) {
  __shared__ __align__(16) unsigned short lK[3][4096];   // 3 x 8 KB
  const int L = blockIdx.x + 8 * (blockIdx.y + 12 * blockIdx.z);  // 0..1535
  const int xcd = L & 7, j = L >> 3;      // hw round-robins wgid%8 -> XCD
  const int split = j & 3;
  const int st = (j >> 2) & 7;
  const int g = xcd + 8 * (j >> 5);       // (b,h) group, 0..47
  const int h = g % H_, b = g / H_;

  const int tid = threadIdx.x;
  const int wid = tid >> 6, lane = tid & 63;
  const int l15 = lane & 15, lhi = lane >> 4;
  const size_t hb = ((size_t)b * H_ + h) * S_;
  const unsigned short* Qbase = Qb + hb * D_;
  const unsigned short* Kbase = Kb + hb * D_;
  const int s0 = st * 256 + wid * 64;     // 64 rows per wave
  const int tb = split * 512;             // 8 tiles of 64

  short8v q[4][2];
#pragma unroll
  for (int rb = 0; rb < 4; ++rb) {
    const unsigned short* qr = Qbase + (size_t)(s0 + rb * 16 + l15) * D_ + lhi * 8;
    q[rb][0] = *(const short8v*)qr;
    q[rb][1] = *(const short8v*)(qr + 32);
  }

  // tile index (within this split's 8 tiles) holding this wave's diagonal
  const int dtile = ((s0 >> 9) == split) ? ((s0 - tb) >> 6) : -1;

  f32x4 sp[4] = {};                       // sp[rb][r] row partial sums
  stageK(Kbase, tb, tid, lK[0]);
  stageK(Kbase, tb + 64, tid, lK[1]);
  int bi = 0;
#pragma unroll 1
  for (int i = 0; i < 7; ++i) {
    VM2;                                   // own tile-i loads done (only i+1 in flight)
    BAR;                                   // tile-i fully visible; compute(i-1) done
    if (i < 6) {
      int bs_ = bi + 2; if (bs_ >= 3) bs_ -= 3;
      stageK(Kbase, tb + (i + 2) * 64, tid, lK[bs_]);
    }
    computeTile64(lK[bi], q, sp, i == dtile, l15, lhi);
    if (++bi == 3) bi = 0;
  }
  VM0; BAR;
  computeTile64(lK[bi], q, sp, 7 == dtile, l15, lhi);

#pragma unroll
  for (int rb = 0; rb < 4; ++rb)
#pragma unroll
    for (int r = 0; r < 4; ++r) {
      float s = sp[rb][r];
#pragma unroll
      for (int off = 1; off < 16; off <<= 1) s += __shfl_xor(s, off, 64);
      if (l15 == 0)
        rowsum[(size_t)split * NROWS + hb + s0 + rb * 16 + lhi * 4 + r] = s;
    }
}

__global__ __launch_bounds__(256) void finish1_kernel(const float* __restrict__ rowsum,
                                                      const float* __restrict__ beta,
                                                      float* __restrict__ partial) {
  int row = blockIdx.x * 256 + threadIdx.x;
  float s = (rowsum[row] + rowsum[NROWS + row]) +
            (rowsum[2 * NROWS + row] + rowsum[3 * NROWS + row]);
  int h = (row >> 11) % H_;
  float c = __builtin_amdgcn_logf(s) * LN2 / beta[h];   // v_log_f32 = log2
#pragma unroll
  for (int off = 1; off < 64; off <<= 1) c += __shfl_xor(c, off, 64);
  __shared__ float wsum[4];
  int wid = threadIdx.x >> 6;
  if ((threadIdx.x & 63) == 0) wsum[wid] = c;
  __syncthreads();
  if (threadIdx.x == 0) partial[blockIdx.x] = wsum[0] + wsum[1] + wsum[2] + wsum[3];
}

__global__ __launch_bounds__(256) void finish2_kernel(const float* __restrict__ partial, int n,
                                                      float* __restrict__ out) {
  float s = 0.f;
  for (int i = threadIdx.x; i < n; i += 256) s += partial[i];
#pragma unroll
  for (int off = 1; off < 64; off <<= 1) s += __shfl_xor(s, off, 64);
  __shared__ float wsum[4];
  int wid = threadIdx.x >> 6;
  if ((threadIdx.x & 63) == 0) wsum[wid] = s;
  __syncthreads();
  if (threadIdx.x == 0) out[0] = -(wsum[0] + wsum[1] + wsum[2] + wsum[3]);
}

extern "C" void kernel_launch(void* const* d_in, const int* in_sizes, int n_in,
                              void* d_out, int out_size, void* d_ws, size_t ws_size,
                              hipStream_t stream) {
  const float* x    = (const float*)d_in[0];
  const float* wq   = (const float*)d_in[1];
  const float* wk   = (const float*)d_in[2];
  const float* beta = (const float*)d_in[3];

  char* ws = (char*)d_ws;
  const size_t wb_bytes = (size_t)2 * H_ * D_ * E_ * 2;    //  2,359,296
  const size_t qk_bytes = (size_t)B_ * H_ * S_ * D_ * 2;   // 12,582,912
  const size_t rs_bytes = (size_t)4 * NROWS * 4;           //   1,572,864
  unsigned short* wb = (unsigned short*)ws;
  unsigned short* Qb = (unsigned short*)(ws + wb_bytes);
  unsigned short* Kb = (unsigned short*)(ws + wb_bytes + qk_bytes);
  float* rowsum      = (float*)(ws + wb_bytes + 2 * qk_bytes);
  float* partial     = (float*)(ws + wb_bytes + 2 * qk_bytes + rs_bytes);

  int nw4 = (H_ * D_ * E_) / 4;
  cvt_w_kernel<<<(2 * nw4 + 255) / 256, 256, 0, stream>>>((const float4*)wq, (const float4*)wk,
                                                          beta, (ushort4*)wb, nw4);

  dim3 pgrid((B_ * S_) / 128, (2 * H_ * D_) / 128);   // 64 x 12
  proj_kernel<<<pgrid, 256, 0, stream>>>(x, wb, Qb, Kb);

  dim3 lgrid(S_ / 256, H_, B_ * 4);                    // 8 x 12 x 16 = 1536 blocks
  lse_kernel<<<lgrid, 256, 0, stream>>>(Qb, Kb, rowsum);

  finish1_kernel<<<NROWS / 256, 256, 0, stream>>>(rowsum, beta, partial);
  finish2_kernel<<<1, 256, 0, stream>>>(partial, NROWS / 256, (float*)d_out);
}

// Round 8
// 77.092 us; speedup vs baseline: 1.0185x; 1.0185x over previous
//
#include <hip/hip_runtime.h>
#include <hip/hip_bf16.h>

typedef __attribute__((ext_vector_type(8))) short short8v;
typedef __attribute__((ext_vector_type(4))) float f32x4;

static constexpr int B_ = 4, S_ = 2048, E_ = 768, H_ = 12, D_ = 64;
static constexpr int NROWS = B_ * H_ * S_;       // 98304
static constexpr float LOG2E = 1.44269504088896340736f;
static constexpr float LN2 = 0.69314718055994530942f;

typedef __attribute__((address_space(3))) unsigned int lds_u32;
typedef const __attribute__((address_space(1))) unsigned int glb_u32;

__device__ __forceinline__ void gload16(const void* g, void* l) {
  __builtin_amdgcn_global_load_lds((glb_u32*)g, (lds_u32*)l, 16, 0, 0);
}

#define VM0 asm volatile("s_waitcnt vmcnt(0)" ::: "memory")
#define VM2 asm volatile("s_waitcnt vmcnt(2)" ::: "memory")
#define LG0 asm volatile("s_waitcnt lgkmcnt(0)" ::: "memory")
#define BAR __builtin_amdgcn_s_barrier()

__device__ __forceinline__ unsigned short f2bf(float f) {
  union { float f; unsigned int u; } v; v.f = f;
  unsigned int u = v.u;
  unsigned int r = (u + 0x7fffu + ((u >> 16) & 1u)) >> 16;
  return (unsigned short)r;
}

// wb[1536][768]: rows 0..767 = beta[h]*log2e*W^Q; rows 768..1535 = W^K
__global__ __launch_bounds__(256) void cvt_w_kernel(const float4* __restrict__ wq,
                                                    const float4* __restrict__ wk,
                                                    const float* __restrict__ beta,
                                                    ushort4* __restrict__ wb, int n4) {
  int i = blockIdx.x * 256 + threadIdx.x;
  if (i < n4) {
    int row = i / (E_ / 4);
    float sc = beta[row >> 6] * LOG2E;
    float4 v = wq[i];
    ushort4 o;
    o.x = f2bf(v.x * sc); o.y = f2bf(v.y * sc); o.z = f2bf(v.z * sc); o.w = f2bf(v.w * sc);
    wb[i] = o;
  } else if (i < 2 * n4) {
    int j = i - n4;
    float4 v = wk[j];
    ushort4 o;
    o.x = f2bf(v.x); o.y = f2bf(v.y); o.z = f2bf(v.z); o.w = f2bf(v.w);
    wb[i] = o;
  }
}

// GEMM: C[8192,1536] = X[8192,768] * W[1536,768]^T, 128x128 tile, BK=32.
// r8 = r6 skeleton (2 barriers/step, the proven 76.3us operating point;
// r7's 1-barrier rewrite regressed -- hand-vmcnt fought the compiler's own
// scoreboard waits) + ONE surgical fix: lB double-buffered and B staged one
// iteration AHEAD (r6 staged B(i) ~30 insts before waiting on it, exposing
// ~1300cy of L2 latency every iteration). Per-iter wait is a single VM2:
// outstanding at that point = [B(i) x2 oldest (aged 1 iter, covered),
// a(i) x4 (aged 1 iter), B(i+1) x2 newest] -> drains B(i)+a(i), leaves
// B(i+1) in flight (never drain to 0). Compiler still inserts its own
// waits for a-reg uses; ours only fences the compiler-untracked gload_lds.
// Hazards: lB[(i+1)&1] last read at compute(i-1) < BAR_top(i) < stage issue;
// returned data drained by VM2(i+1) < BAR_bot(i+1) < reads. lA single-buf:
// write after BAR_top(i), reads after BAR_bot(i), prev reads < BAR_top(i).
__global__ __launch_bounds__(256) void proj_kernel(const float* __restrict__ x,
                                                   const unsigned short* __restrict__ wb,
                                                   unsigned short* __restrict__ Qb,
                                                   unsigned short* __restrict__ Kb) {
  __shared__ unsigned short lA[128 * 32];       // 8 KB bf16, LDS[r][c]=X[r][c^(r&3)]
  __shared__ unsigned short lB[2][128 * 32];    // 2 x 8 KB bf16, same swizzle
  const int mt = blockIdx.x, nt = blockIdx.y;
  const int t = threadIdx.x;
  const int wid = t >> 6, lane = t & 63, l15 = lane & 15, lhi = lane >> 4;
  const int wr = (wid >> 1) * 64, wc = (wid & 1) * 64;

  f32x4 acc[4][4] = {};

  const int row = t >> 2, ch = t & 3;           // row 0..63, dest chunk 0..3
  const int chs = ch ^ (row & 3);               // inverse-swizzled source chunk
  const float* gA = x + (size_t)(mt * 128 + row) * E_ + chs * 8;
  const unsigned short* gB = wb + (size_t)(nt * 128 + row) * E_ + chs * 8;

  // prologue: B(0) stage first (oldest), then a(0) reg loads
  gload16(gB, &lB[0][t * 8]);
  gload16(gB + (size_t)64 * E_, &lB[0][2048 + t * 8]);
  f32x4 a0 = *(const f32x4*)(gA);
  f32x4 a1 = *(const f32x4*)(gA + 4);
  f32x4 a2 = *(const f32x4*)(gA + 64 * E_);
  f32x4 a3 = *(const f32x4*)(gA + 64 * E_ + 4);

#pragma unroll 1
  for (int i = 0; i < 24; ++i) {
    const int k0 = i * 32;
    BAR;                                        // compute(i-1) done: lA, lB[(i+1)&1] reusable
    if (i < 23) {                               // stage B(i+1) one iteration ahead
      gload16(gB + k0 + 32, &lB[(i + 1) & 1][t * 8]);
      gload16(gB + (size_t)64 * E_ + k0 + 32, &lB[(i + 1) & 1][2048 + t * 8]);
    }
    VM2;                                        // B(i)+a(i) drained; B(i+1) stays in flight
    union { short8v s8; unsigned int u[4]; } c0, c1;
    asm("v_cvt_pk_bf16_f32 %0, %1, %2" : "=v"(c0.u[0]) : "v"(a0[0]), "v"(a0[1]));
    asm("v_cvt_pk_bf16_f32 %0, %1, %2" : "=v"(c0.u[1]) : "v"(a0[2]), "v"(a0[3]));
    asm("v_cvt_pk_bf16_f32 %0, %1, %2" : "=v"(c0.u[2]) : "v"(a1[0]), "v"(a1[1]));
    asm("v_cvt_pk_bf16_f32 %0, %1, %2" : "=v"(c0.u[3]) : "v"(a1[2]), "v"(a1[3]));
    asm("v_cvt_pk_bf16_f32 %0, %1, %2" : "=v"(c1.u[0]) : "v"(a2[0]), "v"(a2[1]));
    asm("v_cvt_pk_bf16_f32 %0, %1, %2" : "=v"(c1.u[1]) : "v"(a2[2]), "v"(a2[3]));
    asm("v_cvt_pk_bf16_f32 %0, %1, %2" : "=v"(c1.u[2]) : "v"(a3[0]), "v"(a3[1]));
    asm("v_cvt_pk_bf16_f32 %0, %1, %2" : "=v"(c1.u[3]) : "v"(a3[2]), "v"(a3[3]));
    *(short8v*)&lA[row * 32 + ch * 8] = c0.s8;          // rows 0..63
    *(short8v*)&lA[(row + 64) * 32 + ch * 8] = c1.s8;   // rows 64..127
    if (i < 23) {                               // a(i+1) reg prefetch (after B(i+1))
      a0 = *(const f32x4*)(gA + k0 + 32);
      a1 = *(const f32x4*)(gA + k0 + 36);
      a2 = *(const f32x4*)(gA + 64 * E_ + k0 + 32);
      a3 = *(const f32x4*)(gA + 64 * E_ + k0 + 36);
    }
    LG0;                                        // own ds_writes visible
    BAR;                                        // lA + lB[i&1] staged block-wide
    short8v aF[4], bF[4];
    const unsigned short* pb = lB[i & 1];
#pragma unroll
    for (int m = 0; m < 4; ++m) {
      const int r = wr + m * 16 + l15;
      aF[m] = *(const short8v*)&lA[r * 32 + ((lhi ^ (l15 & 3)) << 3)];
    }
#pragma unroll
    for (int n = 0; n < 4; ++n) {
      const int r = wc + n * 16 + l15;
      bF[n] = *(const short8v*)&pb[r * 32 + ((lhi ^ (l15 & 3)) << 3)];
    }
#pragma unroll
    for (int m = 0; m < 4; ++m)
#pragma unroll
      for (int n = 0; n < 4; ++n)
        acc[m][n] = __builtin_amdgcn_mfma_f32_16x16x32_bf16(aF[m], bF[n], acc[m][n], 0, 0, 0);
  }

  const int nbase = nt * 128 + wc;
  unsigned short* dst = (nbase < 768) ? Qb : Kb;
  const int nb = (nbase < 768) ? nbase : nbase - 768;
#pragma unroll
  for (int m = 0; m < 4; ++m)
#pragma unroll
    for (int n = 0; n < 4; ++n)
#pragma unroll
      for (int r = 0; r < 4; ++r) {
        int M = mt * 128 + wr + m * 16 + lhi * 4 + r;
        int col = nb + n * 16 + l15;
        int h = col >> 6, d = col & 63;
        int b = M >> 11, s = M & (S_ - 1);
        dst[((((size_t)b * H_ + h) * S_ + s) << 6) + d] = f2bf(acc[m][n][r]);
      }
}

// Stage one 64-row K tile (8 KB) into LDS (256 threads), XOR-swizzled via
// pre-swizzled global source (rule #21: linear LDS dest).
// LDS[row][slot] (16B chunks, slot=0..7) = K[row][slot ^ (row&7)].
__device__ __forceinline__ void stageK(const unsigned short* __restrict__ Kbase, int t0,
                                       int tid, unsigned short* lbuf) {
  const int w = tid >> 6;
  const int r = tid >> 3;                       // 0..31
  const int c = (tid & 7) ^ (r & 7);            // inverse-swizzled source chunk
  const char* src = (const char*)Kbase + ((size_t)(t0 + r) << 7) + (c << 4);
  char* ldst = (char*)lbuf + (w << 10);         // wave-uniform; HW adds lane*16
  gload16(src, ldst);
  gload16(src + (32 << 7), ldst + 4096);        // rows 32..63, same swizzle
}

// 64 q-rows per wave: K-fragments read once from LDS feed 4 row-blocks.
// Diagonal self-exclusion folded in (bit-exact r1-r7): zero the diag
// element of fragment (rb==f) instead of a separate correction pass.
__device__ __forceinline__ void computeTile64(const unsigned short* lbuf, const short8v q[4][2],
                                              f32x4 sp[4], bool isD, int l15, int lhi) {
  short8v kf[4][2];
  const int sw = l15 & 7;
#pragma unroll
  for (int f = 0; f < 4; ++f) {
    const char* p = (const char*)lbuf + ((f * 16 + l15) << 7);
    kf[f][0] = *(const short8v*)(p + ((lhi ^ sw) << 4));
    kf[f][1] = *(const short8v*)(p + (((lhi + 4) ^ sw) << 4));
  }
#pragma unroll
  for (int rb = 0; rb < 4; ++rb) {
    f32x4 acc[4] = {};
#pragma unroll
    for (int f = 0; f < 4; ++f) {
      acc[f] = __builtin_amdgcn_mfma_f32_16x16x32_bf16(q[rb][0], kf[f][0], acc[f], 0, 0, 0);
      acc[f] = __builtin_amdgcn_mfma_f32_16x16x32_bf16(q[rb][1], kf[f][1], acc[f], 0, 0, 0);
    }
#pragma unroll
    for (int f = 0; f < 4; ++f) {
      f32x4 e;
#pragma unroll
      for (int r = 0; r < 4; ++r) e[r] = __builtin_amdgcn_exp2f(acc[f][r]);
      if (isD && f == rb) {
#pragma unroll
        for (int r = 0; r < 4; ++r)
          if (l15 == lhi * 4 + r) e[r] = 0.f;
      }
      sp[rb] += e;                        // v_pk_add_f32 x2
    }
  }
}

// LSE row sums. 4 waves x 64 rows = 256 rows/block; t-range split in 4
// (8 tiles/block). 3-buffer rotation, one barrier per tile (proven best
// operating point across r0-r7: deeper pipelines/LDS-free/reg-dbuf all
// regress or tie; lse plateaus at ~45us, exp2-VALU dominated).
__global__ __launch_bounds__(256) void lse_kernel(const unsigned short* __restrict__ Qb,
                                                  const unsigned short* __restrict__ Kb,
                                                  float* __restrict__ rowsum) {
  __shared__ __align__(16) unsigned short lK[3][4096];   // 3 x 8 KB
  const int L = blockIdx.x + 8 * (blockIdx.y + 12 * blockIdx.z);  // 0..1535
  const int xcd = L & 7, j = L >> 3;      // hw round-robins wgid%8 -> XCD
  const int split = j & 3;
  const int st = (j >> 2) & 7;
  const int g = xcd + 8 * (j >> 5);       // (b,h) group, 0..47
  const int h = g % H_, b = g / H_;

  const int tid = threadIdx.x;
  const int wid = tid >> 6, lane = tid & 63;
  const int l15 = lane & 15, lhi = lane >> 4;
  const size_t hb = ((size_t)b * H_ + h) * S_;
  const unsigned short* Qbase = Qb + hb * D_;
  const unsigned short* Kbase = Kb + hb * D_;
  const int s0 = st * 256 + wid * 64;     // 64 rows per wave
  const int tb = split * 512;             // 8 tiles of 64

  short8v q[4][2];
#pragma unroll
  for (int rb = 0; rb < 4; ++rb) {
    const unsigned short* qr = Qbase + (size_t)(s0 + rb * 16 + l15) * D_ + lhi * 8;
    q[rb][0] = *(const short8v*)qr;
    q[rb][1] = *(const short8v*)(qr + 32);
  }

  // tile index (within this split's 8 tiles) holding this wave's diagonal
  const int dtile = ((s0 >> 9) == split) ? ((s0 - tb) >> 6) : -1;

  f32x4 sp[4] = {};                       // sp[rb][r] row partial sums
  stageK(Kbase, tb, tid, lK[0]);
  stageK(Kbase, tb + 64, tid, lK[1]);
  int bi = 0;
#pragma unroll 1
  for (int i = 0; i < 7; ++i) {
    VM2;                                   // own tile-i loads done (only i+1 in flight)
    BAR;                                   // tile-i fully visible; compute(i-1) done
    if (i < 6) {
      int bs_ = bi + 2; if (bs_ >= 3) bs_ -= 3;
      stageK(Kbase, tb + (i + 2) * 64, tid, lK[bs_]);
    }
    computeTile64(lK[bi], q, sp, i == dtile, l15, lhi);
    if (++bi == 3) bi = 0;
  }
  VM0; BAR;
  computeTile64(lK[bi], q, sp, 7 == dtile, l15, lhi);

#pragma unroll
  for (int rb = 0; rb < 4; ++rb)
#pragma unroll
    for (int r = 0; r < 4; ++r) {
      float s = sp[rb][r];
#pragma unroll
      for (int off = 1; off < 16; off <<= 1) s += __shfl_xor(s, off, 64);
      if (l15 == 0)
        rowsum[(size_t)split * NROWS + hb + s0 + rb * 16 + lhi * 4 + r] = s;
    }
}

__global__ __launch_bounds__(256) void finish1_kernel(const float* __restrict__ rowsum,
                                                      const float* __restrict__ beta,
                                                      float* __restrict__ partial) {
  int row = blockIdx.x * 256 + threadIdx.x;
  float s = (rowsum[row] + rowsum[NROWS + row]) +
            (rowsum[2 * NROWS + row] + rowsum[3 * NROWS + row]);
  int h = (row >> 11) % H_;
  float c = __builtin_amdgcn_logf(s) * LN2 / beta[h];   // v_log_f32 = log2
#pragma unroll
  for (int off = 1; off < 64; off <<= 1) c += __shfl_xor(c, off, 64);
  __shared__ float wsum[4];
  int wid = threadIdx.x >> 6;
  if ((threadIdx.x & 63) == 0) wsum[wid] = c;
  __syncthreads();
  if (threadIdx.x == 0) partial[blockIdx.x] = wsum[0] + wsum[1] + wsum[2] + wsum[3];
}

__global__ __launch_bounds__(256) void finish2_kernel(const float* __restrict__ partial, int n,
                                                      float* __restrict__ out) {
  float s = 0.f;
  for (int i = threadIdx.x; i < n; i += 256) s += partial[i];
#pragma unroll
  for (int off = 1; off < 64; off <<= 1) s += __shfl_xor(s, off, 64);
  __shared__ float wsum[4];
  int wid = threadIdx.x >> 6;
  if ((threadIdx.x & 63) == 0) wsum[wid] = s;
  __syncthreads();
  if (threadIdx.x == 0) out[0] = -(wsum[0] + wsum[1] + wsum[2] + wsum[3]);
}

extern "C" void kernel_launch(void* const* d_in, const int* in_sizes, int n_in,
                              void* d_out, int out_size, void* d_ws, size_t ws_size,
                              hipStream_t stream) {
  const float* x    = (const float*)d_in[0];
  const float* wq   = (const float*)d_in[1];
  const float* wk   = (const float*)d_in[2];
  const float* beta = (const float*)d_in[3];

  char* ws = (char*)d_ws;
  const size_t wb_bytes = (size_t)2 * H_ * D_ * E_ * 2;    //  2,359,296
  const size_t qk_bytes = (size_t)B_ * H_ * S_ * D_ * 2;   // 12,582,912
  const size_t rs_bytes = (size_t)4 * NROWS * 4;           //   1,572,864
  unsigned short* wb = (unsigned short*)ws;
  unsigned short* Qb = (unsigned short*)(ws + wb_bytes);
  unsigned short* Kb = (unsigned short*)(ws + wb_bytes + qk_bytes);
  float* rowsum      = (float*)(ws + wb_bytes + 2 * qk_bytes);
  float* partial     = (float*)(ws + wb_bytes + 2 * qk_bytes + rs_bytes);

  int nw4 = (H_ * D_ * E_) / 4;
  cvt_w_kernel<<<(2 * nw4 + 255) / 256, 256, 0, stream>>>((const float4*)wq, (const float4*)wk,
                                                          beta, (ushort4*)wb, nw4);

  dim3 pgrid((B_ * S_) / 128, (2 * H_ * D_) / 128);   // 64 x 12
  proj_kernel<<<pgrid, 256, 0, stream>>>(x, wb, Qb, Kb);

  dim3 lgrid(S_ / 256, H_, B_ * 4);                    // 8 x 12 x 16 = 1536 blocks
  lse_kernel<<<lgrid, 256, 0, stream>>>(Qb, Kb, rowsum);

  finish1_kernel<<<NROWS / 256, 256, 0, stream>>>(rowsum, beta, partial);
  finish2_kernel<<<1, 256, 0, stream>>>(partial, NROWS / 256, (float*)d_out);
}

// Round 9
// 75.630 us; speedup vs baseline: 1.0382x; 1.0193x over previous
//
#include <hip/hip_runtime.h>
#include <hip/hip_bf16.h>

typedef __attribute__((ext_vector_type(8))) short short8v;
typedef __attribute__((ext_vector_type(4))) float f32x4;

static constexpr int B_ = 4, S_ = 2048, E_ = 768, H_ = 12, D_ = 64;
static constexpr int NROWS = B_ * H_ * S_;       // 98304
static constexpr float LOG2E = 1.44269504088896340736f;
static constexpr float LN2 = 0.69314718055994530942f;

typedef __attribute__((address_space(3))) unsigned int lds_u32;
typedef const __attribute__((address_space(1))) unsigned int glb_u32;

__device__ __forceinline__ void gload16(const void* g, void* l) {
  __builtin_amdgcn_global_load_lds((glb_u32*)g, (lds_u32*)l, 16, 0, 0);
}

#define VM0 asm volatile("s_waitcnt vmcnt(0)" ::: "memory")
#define VM2 asm volatile("s_waitcnt vmcnt(2)" ::: "memory")
#define VM4 asm volatile("s_waitcnt vmcnt(4)" ::: "memory")
#define VM8 asm volatile("s_waitcnt vmcnt(8)" ::: "memory")
#define LG0 asm volatile("s_waitcnt lgkmcnt(0)" ::: "memory")
#define BAR __builtin_amdgcn_s_barrier()

__device__ __forceinline__ unsigned short f2bf(float f) {
  union { float f; unsigned int u; } v; v.f = f;
  unsigned int u = v.u;
  unsigned int r = (u + 0x7fffu + ((u >> 16) & 1u)) >> 16;
  return (unsigned short)r;
}

// wb[1536][768]: rows 0..767 = beta[h]*log2e*W^Q; rows 768..1535 = W^K
__global__ __launch_bounds__(256) void cvt_w_kernel(const float4* __restrict__ wq,
                                                    const float4* __restrict__ wk,
                                                    const float* __restrict__ beta,
                                                    ushort4* __restrict__ wb, int n4) {
  int i = blockIdx.x * 256 + threadIdx.x;
  if (i < n4) {
    int row = i / (E_ / 4);
    float sc = beta[row >> 6] * LOG2E;
    float4 v = wq[i];
    ushort4 o;
    o.x = f2bf(v.x * sc); o.y = f2bf(v.y * sc); o.z = f2bf(v.z * sc); o.w = f2bf(v.w * sc);
    wb[i] = o;
  } else if (i < 2 * n4) {
    int j = i - n4;
    float4 v = wk[j];
    ushort4 o;
    o.x = f2bf(v.x); o.y = f2bf(v.y); o.z = f2bf(v.z); o.w = f2bf(v.w);
    wb[i] = o;
  }
}

// GEMM: C[8192,1536] = X[8192,768] * W[1536,768]^T, 128x128 tile, BK=64.
// r9 = r6's proven 2-barrier schedule with the K-step DOUBLED: 12 iters
// (was 24) -> barrier drains halved, MFMA per drain doubled. proj is
// grid-limited at exactly 3 blocks/CU (768 blocks), so LDS 32KB and the
// VGPR growth are free; __launch_bounds__(256,3) pins regalloc to the
// grid-given 3 waves/EU. Rows are now 128B (8 x 16B chunks) = lse stageK
// geometry: swizzle LDS[r][c] = src[r][c^(r&7)] on both A (reg-staged,
// linear ds_write dest + inverse-swz source) and B (gload_lds linear dest
// + pre-swz source). Counted waits (never 0 until last step):
//   VM4: outstanding = [a(i) x8 old, B(i) x4 new] -> drains a(i) only
//   VM8: outstanding = [B(i) x4 old, a(i+1) x8 new] -> drains B(i) only
// Fragments read per k-half (ks=0,1) to cap live frag regs at 32.
__global__ __launch_bounds__(256, 3) void proj_kernel(const float* __restrict__ x,
                                                      const unsigned short* __restrict__ wb,
                                                      unsigned short* __restrict__ Qb,
                                                      unsigned short* __restrict__ Kb) {
  __shared__ unsigned short lA[128 * 64];       // 16 KB bf16
  __shared__ unsigned short lB[128 * 64];       // 16 KB bf16
  const int mt = blockIdx.x, nt = blockIdx.y;
  const int t = threadIdx.x;
  const int wid = t >> 6, lane = t & 63, l15 = lane & 15, lhi = lane >> 4;
  const int wr = (wid >> 1) * 64, wc = (wid & 1) * 64;

  f32x4 acc[4][4] = {};

  // staging geometry: linear chunk idx = j*256 + t -> row = j*32 + (t>>3),
  // dest chunk = t&7, source chunk = (t&7) ^ (row&7)
  const int r0 = t >> 3;                        // 0..31
  const int cs = (t & 7) ^ (r0 & 7);            // inverse-swizzled source chunk
  const float* gA = x + (size_t)(mt * 128 + r0) * E_ + cs * 8;
  const unsigned short* gB = wb + (size_t)(nt * 128 + r0) * E_ + cs * 8;

  // prologue: a(0) = 8 f32x4 (rows r0, r0+32, r0+64, r0+96; cols cs*8..+7)
  f32x4 a0 = *(const f32x4*)(gA);
  f32x4 a1 = *(const f32x4*)(gA + 4);
  f32x4 a2 = *(const f32x4*)(gA + 32 * E_);
  f32x4 a3 = *(const f32x4*)(gA + 32 * E_ + 4);
  f32x4 a4 = *(const f32x4*)(gA + 64 * E_);
  f32x4 a5 = *(const f32x4*)(gA + 64 * E_ + 4);
  f32x4 a6 = *(const f32x4*)(gA + 96 * E_);
  f32x4 a7 = *(const f32x4*)(gA + 96 * E_ + 4);

#pragma unroll 1
  for (int i = 0; i < 12; ++i) {
    const int k0 = i * 64;
    BAR;                                        // compute(i-1) done: lA/lB reusable
    gload16(gB + k0,            &lB[t * 8]);            // rows  0..31
    gload16(gB + 32 * E_ + k0,  &lB[2048 + t * 8]);     // rows 32..63
    gload16(gB + 64 * E_ + k0,  &lB[4096 + t * 8]);     // rows 64..95
    gload16(gB + 96 * E_ + k0,  &lB[6144 + t * 8]);     // rows 96..127
    VM4;                                        // a(i) landed; B(i) in flight
    union { short8v s8; unsigned int u[4]; } c0, c1, c2, c3;
    asm("v_cvt_pk_bf16_f32 %0, %1, %2" : "=v"(c0.u[0]) : "v"(a0[0]), "v"(a0[1]));
    asm("v_cvt_pk_bf16_f32 %0, %1, %2" : "=v"(c0.u[1]) : "v"(a0[2]), "v"(a0[3]));
    asm("v_cvt_pk_bf16_f32 %0, %1, %2" : "=v"(c0.u[2]) : "v"(a1[0]), "v"(a1[1]));
    asm("v_cvt_pk_bf16_f32 %0, %1, %2" : "=v"(c0.u[3]) : "v"(a1[2]), "v"(a1[3]));
    asm("v_cvt_pk_bf16_f32 %0, %1, %2" : "=v"(c1.u[0]) : "v"(a2[0]), "v"(a2[1]));
    asm("v_cvt_pk_bf16_f32 %0, %1, %2" : "=v"(c1.u[1]) : "v"(a2[2]), "v"(a2[3]));
    asm("v_cvt_pk_bf16_f32 %0, %1, %2" : "=v"(c1.u[2]) : "v"(a3[0]), "v"(a3[1]));
    asm("v_cvt_pk_bf16_f32 %0, %1, %2" : "=v"(c1.u[3]) : "v"(a3[2]), "v"(a3[3]));
    asm("v_cvt_pk_bf16_f32 %0, %1, %2" : "=v"(c2.u[0]) : "v"(a4[0]), "v"(a4[1]));
    asm("v_cvt_pk_bf16_f32 %0, %1, %2" : "=v"(c2.u[1]) : "v"(a4[2]), "v"(a4[3]));
    asm("v_cvt_pk_bf16_f32 %0, %1, %2" : "=v"(c2.u[2]) : "v"(a5[0]), "v"(a5[1]));
    asm("v_cvt_pk_bf16_f32 %0, %1, %2" : "=v"(c2.u[3]) : "v"(a5[2]), "v"(a5[3]));
    asm("v_cvt_pk_bf16_f32 %0, %1, %2" : "=v"(c3.u[0]) : "v"(a6[0]), "v"(a6[1]));
    asm("v_cvt_pk_bf16_f32 %0, %1, %2" : "=v"(c3.u[1]) : "v"(a6[2]), "v"(a6[3]));
    asm("v_cvt_pk_bf16_f32 %0, %1, %2" : "=v"(c3.u[2]) : "v"(a7[0]), "v"(a7[1]));
    asm("v_cvt_pk_bf16_f32 %0, %1, %2" : "=v"(c3.u[3]) : "v"(a7[2]), "v"(a7[3]));
    *(short8v*)&lA[t * 8]        = c0.s8;
    *(short8v*)&lA[2048 + t * 8] = c1.s8;
    *(short8v*)&lA[4096 + t * 8] = c2.s8;
    *(short8v*)&lA[6144 + t * 8] = c3.s8;
    if (i < 11) {                               // a(i+1) reg prefetch
      a0 = *(const f32x4*)(gA + k0 + 64);
      a1 = *(const f32x4*)(gA + k0 + 68);
      a2 = *(const f32x4*)(gA + 32 * E_ + k0 + 64);
      a3 = *(const f32x4*)(gA + 32 * E_ + k0 + 68);
      a4 = *(const f32x4*)(gA + 64 * E_ + k0 + 64);
      a5 = *(const f32x4*)(gA + 64 * E_ + k0 + 68);
      a6 = *(const f32x4*)(gA + 96 * E_ + k0 + 64);
      a7 = *(const f32x4*)(gA + 96 * E_ + k0 + 68);
    }
    LG0;                                        // own ds_writes visible
    if (i < 11) { VM8; } else { VM0; }          // B(i) landed; a(i+1) in flight
    BAR;                                        // lA + lB staged block-wide
#pragma unroll
    for (int ks = 0; ks < 2; ++ks) {
      const int co = ks * 4;
      short8v aF[4], bF[4];
#pragma unroll
      for (int m = 0; m < 4; ++m) {
        const int r = wr + m * 16 + l15;
        aF[m] = *(const short8v*)&lA[r * 64 + (((co + lhi) ^ (l15 & 7)) << 3)];
      }
#pragma unroll
      for (int n = 0; n < 4; ++n) {
        const int r = wc + n * 16 + l15;
        bF[n] = *(const short8v*)&lB[r * 64 + (((co + lhi) ^ (l15 & 7)) << 3)];
      }
#pragma unroll
      for (int m = 0; m < 4; ++m)
#pragma unroll
        for (int n = 0; n < 4; ++n)
          acc[m][n] = __builtin_amdgcn_mfma_f32_16x16x32_bf16(aF[m], bF[n], acc[m][n], 0, 0, 0);
    }
  }

  const int nbase = nt * 128 + wc;
  unsigned short* dst = (nbase < 768) ? Qb : Kb;
  const int nb = (nbase < 768) ? nbase : nbase - 768;
#pragma unroll
  for (int m = 0; m < 4; ++m)
#pragma unroll
    for (int n = 0; n < 4; ++n)
#pragma unroll
      for (int r = 0; r < 4; ++r) {
        int M = mt * 128 + wr + m * 16 + lhi * 4 + r;
        int col = nb + n * 16 + l15;
        int h = col >> 6, d = col & 63;
        int b = M >> 11, s = M & (S_ - 1);
        dst[((((size_t)b * H_ + h) * S_ + s) << 6) + d] = f2bf(acc[m][n][r]);
      }
}

// Stage one 64-row K tile (8 KB) into LDS (256 threads), XOR-swizzled via
// pre-swizzled global source (rule #21: linear LDS dest).
// LDS[row][slot] (16B chunks, slot=0..7) = K[row][slot ^ (row&7)].
__device__ __forceinline__ void stageK(const unsigned short* __restrict__ Kbase, int t0,
                                       int tid, unsigned short* lbuf) {
  const int w = tid >> 6;
  const int r = tid >> 3;                       // 0..31
  const int c = (tid & 7) ^ (r & 7);            // inverse-swizzled source chunk
  const char* src = (const char*)Kbase + ((size_t)(t0 + r) << 7) + (c << 4);
  char* ldst = (char*)lbuf + (w << 10);         // wave-uniform; HW adds lane*16
  gload16(src, ldst);
  gload16(src + (32 << 7), ldst + 4096);        // rows 32..63, same swizzle
}

// 64 q-rows per wave: K-fragments read once from LDS feed 4 row-blocks.
// Diagonal self-exclusion folded in (bit-exact r1-r8): zero the diag
// element of fragment (rb==f) instead of a separate correction pass.
__device__ __forceinline__ void computeTile64(const unsigned short* lbuf, const short8v q[4][2],
                                              f32x4 sp[4], bool isD, int l15, int lhi) {
  short8v kf[4][2];
  const int sw = l15 & 7;
#pragma unroll
  for (int f = 0; f < 4; ++f) {
    const char* p = (const char*)lbuf + ((f * 16 + l15) << 7);
    kf[f][0] = *(const short8v*)(p + ((lhi ^ sw) << 4));
    kf[f][1] = *(const short8v*)(p + (((lhi + 4) ^ sw) << 4));
  }
#pragma unroll
  for (int rb = 0; rb < 4; ++rb) {
    f32x4 acc[4] = {};
#pragma unroll
    for (int f = 0; f < 4; ++f) {
      acc[f] = __builtin_amdgcn_mfma_f32_16x16x32_bf16(q[rb][0], kf[f][0], acc[f], 0, 0, 0);
      acc[f] = __builtin_amdgcn_mfma_f32_16x16x32_bf16(q[rb][1], kf[f][1], acc[f], 0, 0, 0);
    }
#pragma unroll
    for (int f = 0; f < 4; ++f) {
      f32x4 e;
#pragma unroll
      for (int r = 0; r < 4; ++r) e[r] = __builtin_amdgcn_exp2f(acc[f][r]);
      if (isD && f == rb) {
#pragma unroll
        for (int r = 0; r < 4; ++r)
          if (l15 == lhi * 4 + r) e[r] = 0.f;
      }
      sp[rb] += e;                        // v_pk_add_f32 x2
    }
  }
}

// LSE row sums. 4 waves x 64 rows = 256 rows/block; t-range split in 4
// (8 tiles/block). 3-buffer rotation, one barrier per tile (proven best
// operating point across r0-r8: deeper pipelines/LDS-free/reg-dbuf all
// regress or tie; lse plateaus at ~45us, exp2-VALU dominated).
__global__ __launch_bounds__(256) void lse_kernel(const unsigned short* __restrict__ Qb,
                                                  const unsigned short* __restrict__ Kb,
                                                  float* __restrict__ rowsum) {
  __shared__ __align__(16) unsigned short lK[3][4096];   // 3 x 8 KB
  const int L = blockIdx.x + 8 * (blockIdx.y + 12 * blockIdx.z);  // 0..1535
  const int xcd = L & 7, j = L >> 3;      // hw round-robins wgid%8 -> XCD
  const int split = j & 3;
  const int st = (j >> 2) & 7;
  const int g = xcd + 8 * (j >> 5);       // (b,h) group, 0..47
  const int h = g % H_, b = g / H_;

  const int tid = threadIdx.x;
  const int wid = tid >> 6, lane = tid & 63;
  const int l15 = lane & 15, lhi = lane >> 4;
  const size_t hb = ((size_t)b * H_ + h) * S_;
  const unsigned short* Qbase = Qb + hb * D_;
  const unsigned short* Kbase = Kb + hb * D_;
  const int s0 = st * 256 + wid * 64;     // 64 rows per wave
  const int tb = split * 512;             // 8 tiles of 64

  short8v q[4][2];
#pragma unroll
  for (int rb = 0; rb < 4; ++rb) {
    const unsigned short* qr = Qbase + (size_t)(s0 + rb * 16 + l15) * D_ + lhi * 8;
    q[rb][0] = *(const short8v*)qr;
    q[rb][1] = *(const short8v*)(qr + 32);
  }

  // tile index (within this split's 8 tiles) holding this wave's diagonal
  const int dtile = ((s0 >> 9) == split) ? ((s0 - tb) >> 6) : -1;

  f32x4 sp[4] = {};                       // sp[rb][r] row partial sums
  stageK(Kbase, tb, tid, lK[0]);
  stageK(Kbase, tb + 64, tid, lK[1]);
  int bi = 0;
#pragma unroll 1
  for (int i = 0; i < 7; ++i) {
    VM2;                                   // own tile-i loads done (only i+1 in flight)
    BAR;                                   // tile-i fully visible; compute(i-1) done
    if (i < 6) {
      int bs_ = bi + 2; if (bs_ >= 3) bs_ -= 3;
      stageK(Kbase, tb + (i + 2) * 64, tid, lK[bs_]);
    }
    computeTile64(lK[bi], q, sp, i == dtile, l15, lhi);
    if (++bi == 3) bi = 0;
  }
  VM0; BAR;
  computeTile64(lK[bi], q, sp, 7 == dtile, l15, lhi);

#pragma unroll
  for (int rb = 0; rb < 4; ++rb)
#pragma unroll
    for (int r = 0; r < 4; ++r) {
      float s = sp[rb][r];
#pragma unroll
      for (int off = 1; off < 16; off <<= 1) s += __shfl_xor(s, off, 64);
      if (l15 == 0)
        rowsum[(size_t)split * NROWS + hb + s0 + rb * 16 + lhi * 4 + r] = s;
    }
}

__global__ __launch_bounds__(256) void finish1_kernel(const float* __restrict__ rowsum,
                                                      const float* __restrict__ beta,
                                                      float* __restrict__ partial) {
  int row = blockIdx.x * 256 + threadIdx.x;
  float s = (rowsum[row] + rowsum[NROWS + row]) +
            (rowsum[2 * NROWS + row] + rowsum[3 * NROWS + row]);
  int h = (row >> 11) % H_;
  float c = __builtin_amdgcn_logf(s) * LN2 / beta[h];   // v_log_f32 = log2
#pragma unroll
  for (int off = 1; off < 64; off <<= 1) c += __shfl_xor(c, off, 64);
  __shared__ float wsum[4];
  int wid = threadIdx.x >> 6;
  if ((threadIdx.x & 63) == 0) wsum[wid] = c;
  __syncthreads();
  if (threadIdx.x == 0) partial[blockIdx.x] = wsum[0] + wsum[1] + wsum[2] + wsum[3];
}

__global__ __launch_bounds__(256) void finish2_kernel(const float* __restrict__ partial, int n,
                                                      float* __restrict__ out) {
  float s = 0.f;
  for (int i = threadIdx.x; i < n; i += 256) s += partial[i];
#pragma unroll
  for (int off = 1; off < 64; off <<= 1) s += __shfl_xor(s, off, 64);
  __shared__ float wsum[4];
  int wid = threadIdx.x >> 6;
  if ((threadIdx.x & 63) == 0) wsum[wid] = s;
  __syncthreads();
  if (threadIdx.x == 0) out[0] = -(wsum[0] + wsum[1] + wsum[2] + wsum[3]);
}

extern "C" void kernel_launch(void* const* d_in, const int* in_sizes, int n_in,
                              void* d_out, int out_size, void* d_ws, size_t ws_size,
                              hipStream_t stream) {
  const float* x    = (const float*)d_in[0];
  const float* wq   = (const float*)d_in[1];
  const float* wk   = (const float*)d_in[2];
  const float* beta = (const float*)d_in[3];

  char* ws = (char*)d_ws;
  const size_t wb_bytes = (size_t)2 * H_ * D_ * E_ * 2;    //  2,359,296
  const size_t qk_bytes = (size_t)B_ * H_ * S_ * D_ * 2;   // 12,582,912
  const size_t rs_bytes = (size_t)4 * NROWS * 4;           //   1,572,864
  unsigned short* wb = (unsigned short*)ws;
  unsigned short* Qb = (unsigned short*)(ws + wb_bytes);
  unsigned short* Kb = (unsigned short*)(ws + wb_bytes + qk_bytes);
  float* rowsum      = (float*)(ws + wb_bytes + 2 * qk_bytes);
  float* partial     = (float*)(ws + wb_bytes + 2 * qk_bytes + rs_bytes);

  int nw4 = (H_ * D_ * E_) / 4;
  cvt_w_kernel<<<(2 * nw4 + 255) / 256, 256, 0, stream>>>((const float4*)wq, (const float4*)wk,
                                                          beta, (ushort4*)wb, nw4);

  dim3 pgrid((B_ * S_) / 128, (2 * H_ * D_) / 128);   // 64 x 12
  proj_kernel<<<pgrid, 256, 0, stream>>>(x, wb, Qb, Kb);

  dim3 lgrid(S_ / 256, H_, B_ * 4);                    // 8 x 12 x 16 = 1536 blocks
  lse_kernel<<<lgrid, 256, 0, stream>>>(Qb, Kb, rowsum);

  finish1_kernel<<<NROWS / 256, 256, 0, stream>>>(rowsum, beta, partial);
  finish2_kernel<<<1, 256, 0, stream>>>(partial, NROWS / 256, (float*)d_out);
}